// Round 1
// baseline (373.632 us; speedup 1.0000x reference)
//
#include <hip/hip_runtime.h>
#include <math.h>

#define BB 32
#define NN 1024
#define FF 10
#define DD 64
#define MM 4
#define RR 8
#define KK 20
#define BNROWS (BB*NN)   // 32768

// ---- workspace layout (float offsets) ----
#define OFF_HIT   0ull           // h_it   [B,N,D]  2097152
#define OFF_XLIN  2097152ull     // x_lin  [B,N,D]  2097152
#define OFF_EIT   4194304ull     // e_it   [B,N]    32768
#define OFF_PIT   4227072ull     // pi_t   [B,M]    128
#define OFF_MIXED 4227200ull     // mixed  [B,N,D]  2097152
#define OFF_SI    6324352ull     // s_i    [B,N]    32768
#define OFF_SJ    6357120ull     // s_j    [B,N]    32768
#define OFF_GNN   7700608ull     // gnn_pre [B,N,D] 2097152
#define OFF_OUTP  9797760ull     // out_pre [B,N,D] 2097152
#define OFF_STAT  11894912ull    // stats 256 + pool num 2048 + pool den 32

__device__ __forceinline__ float wave_sum(float v) {
    #pragma unroll
    for (int off = 32; off; off >>= 1) v += __shfl_xor(v, off);
    return v;
}
__device__ __forceinline__ float wave_max(float v) {
    #pragma unroll
    for (int off = 32; off; off >>= 1) v = fmaxf(v, __shfl_xor(v, off));
    return v;
}

// ---------------- K1a: per-row h_it, x_lin, e_it (+ zero accum buffers) ----------------
__global__ __launch_bounds__(256) void k_rows(
    const float* __restrict__ data, const float* __restrict__ W_cond,
    const float* __restrict__ b_cond, const float* __restrict__ W_ap,
    const float* __restrict__ b_ap, const float* __restrict__ W_av,
    const float* __restrict__ W_gnn,
    float* __restrict__ h_it, float* __restrict__ x_lin, float* __restrict__ e_it,
    float* __restrict__ stats)
{
    if (blockIdx.x < 10) {
        int idx = blockIdx.x * 256 + threadIdx.x;
        if (idx < 2336) stats[idx] = 0.f;    // stats(256) + num(2048) + den(32)
    }
    int w = threadIdx.x >> 6, lane = threadIdx.x & 63;
    int r = blockIdx.x * 4 + w;               // row in [0, B*N)
    const float* dr = data + r * FF;
    float df[FF];
    #pragma unroll
    for (int f = 0; f < FF; f++) df[f] = dr[f];
    float h = b_cond[lane], x = 0.f;
    #pragma unroll
    for (int f = 0; f < FF; f++) {
        h = fmaf(df[f], W_cond[f * DD + lane], h);
        x = fmaf(df[f], W_gnn[f * DD + lane], x);
    }
    h_it[r * DD + lane] = h;
    x_lin[r * DD + lane] = x;
    float acc = b_ap[lane];
    #pragma unroll
    for (int e2 = 0; e2 < DD; e2++)
        acc = fmaf(__shfl(h, e2), W_ap[e2 * DD + lane], acc);
    float lr = acc > 0.f ? acc : 0.2f * acc;
    float ep = wave_sum(lr * W_av[lane]);
    if (lane == 0) e_it[r] = ep;
}

// ---------------- K1b: parallel pool partials (no max shift; |e| small) ----------------
__global__ __launch_bounds__(256) void k_pool2(
    const float* __restrict__ e_it, const float* __restrict__ h_it,
    float* __restrict__ num, float* __restrict__ den)
{
    int w = threadIdx.x >> 6, lane = threadIdx.x & 63;
    int b = blockIdx.x >> 3, ch = blockIdx.x & 7;
    int base = b * NN + ch * 128 + w * 32;
    float acc = 0.f, dn = 0.f;
    #pragma unroll 4
    for (int i = 0; i < 32; i++) {
        float e = e_it[base + i];
        float wgt = expf(e);
        acc = fmaf(wgt, h_it[(size_t)(base + i) * DD + lane], acc);
        dn += wgt;
    }
    __shared__ float pa[4][DD];
    __shared__ float pd[4];
    pa[w][lane] = acc;
    if (lane == 0) pd[w] = dn;
    __syncthreads();
    if (w == 0) {
        float s = pa[0][lane] + pa[1][lane] + pa[2][lane] + pa[3][lane];
        atomicAdd(&num[b * DD + lane], s);
        if (lane == 0) atomicAdd(&den[b], pd[0] + pd[1] + pd[2] + pd[3]);
    }
}

// ---------------- K2: routing + h_sys normalize ----------------
__global__ void k_route(const float* __restrict__ num, const float* __restrict__ den,
                        const float* __restrict__ W_r, const float* __restrict__ b_r,
                        const float* __restrict__ gumbel,
                        float* __restrict__ h_sys, float* __restrict__ pi_soft,
                        float* __restrict__ pi_t)
{
    int tid = threadIdx.x;
    for (int i = tid; i < BB * DD; i += 256)
        h_sys[i] = num[i] / den[i >> 6];
    if (tid >= BB) return;
    int b = tid;
    float inv = 1.0f / den[b];
    float lg[MM];
    #pragma unroll
    for (int m = 0; m < MM; m++) lg[m] = b_r[m] + gumbel[b * MM + m];
    for (int d = 0; d < DD; d++) {
        float hv = num[b * DD + d] * inv;
        #pragma unroll
        for (int m = 0; m < MM; m++) lg[m] = fmaf(hv, W_r[d * MM + m], lg[m]);
    }
    float mx = fmaxf(fmaxf(lg[0], lg[1]), fmaxf(lg[2], lg[3]));
    float s = 0.f, p[MM];
    #pragma unroll
    for (int m = 0; m < MM; m++) { p[m] = expf(lg[m] - mx); s += p[m]; }
    #pragma unroll
    for (int m = 0; m < MM; m++) { p[m] /= s; pi_soft[b * MM + m] = p[m]; }
    int i1 = 0; float v1 = p[0];
    #pragma unroll
    for (int m = 1; m < MM; m++) if (p[m] > v1) { v1 = p[m]; i1 = m; }
    int i2 = -1; float v2 = -1.f;
    #pragma unroll
    for (int m = 0; m < MM; m++) if (m != i1 && p[m] > v2) { v2 = p[m]; i2 = m; }
    float norm = fmaxf(v1 + v2, 1e-12f);
    #pragma unroll
    for (int m = 0; m < MM; m++)
        pi_t[b * MM + m] = (m == i1 ? v1 : (m == i2 ? v2 : 0.f)) / norm;
}

// ---------------- K3: mixed embeddings + s_i/s_j (wave per row) ----------------
__global__ __launch_bounds__(256) void k_mixed(
    const float* __restrict__ e_base, const float* __restrict__ lr_u,
    const float* __restrict__ lr_v, const float* __restrict__ pi_t,
    const float* __restrict__ x_lin,
    const float* __restrict__ att_i, const float* __restrict__ att_j,
    const float* __restrict__ att_em_i, const float* __restrict__ att_em_j,
    float* __restrict__ mixed, float* __restrict__ s_i, float* __restrict__ s_j)
{
    int w = threadIdx.x >> 6, lane = threadIdx.x & 63;
    int r = blockIdx.x * 4 + w;
    int b = r >> 10, n = r & 1023;
    float LR[MM];
    #pragma unroll
    for (int m = 0; m < MM; m++) {
        float a = 0.f;
        #pragma unroll
        for (int rr = 0; rr < RR; rr++)
            a = fmaf(lr_u[(m * NN + n) * RR + rr], lr_v[(m * RR + rr) * DD + lane], a);
        LR[m] = a;
    }
    float eb = e_base[n * DD + lane];
    float mx = 0.f;
    #pragma unroll
    for (int m = 0; m < MM; m++) mx = fmaf(pi_t[b * MM + m], eb + LR[m], mx);
    mixed[(size_t)r * DD + lane] = mx;
    float x = x_lin[(size_t)r * DD + lane];
    float r1 = wave_sum(x * att_i[lane] + mx * att_em_i[lane]);
    float r2 = wave_sum(x * att_j[lane] + mx * att_em_j[lane]);
    if (lane == 0) { s_i[r] = r1; s_j[r] = r2; }
}

// ---------------- K4: FUSED score GEMM + top-20 selection + GAT + bn1 stats ----------------
// block = 512 thr = 8 waves; each wave owns 4 rows; block owns 32 rows of one batch.
// GEMM: acc[rr][c*4+q] = score(i0+w*4+rr, j=c*256+lane*4+q) — exactly the selection's
// per-lane layout, so top-k runs on registers; the 128 MB score tensor never exists.
__global__ __launch_bounds__(512) void k_fused(
    const float* __restrict__ mixed, const float* __restrict__ x_lin,
    const float* __restrict__ s_i, const float* __restrict__ s_j,
    const float* __restrict__ b_gnn, float* __restrict__ gnn_pre,
    float* __restrict__ stats)
{
    __shared__ float As[32 * DD];      // 8 KB   A tile, broadcast reads (conflict-free)
    __shared__ float BT[DD * 256];     // 64 KB  d-major transposed B chunk

    int t = threadIdx.x;
    int w = t >> 6, lane = t & 63;
    int b = blockIdx.x >> 5;           // batch
    int it = blockIdx.x & 31;          // i-tile
    int i0 = it * 32;
    const float* mb = mixed + (size_t)b * NN * DD;

    // stage A tile: 32x64 floats, one float4 per thread
    *(float4*)&As[t * 4] = *(const float4*)(mb + (size_t)i0 * DD + t * 4);

    float acc[4][16];
    #pragma unroll
    for (int a = 0; a < 4; a++)
        #pragma unroll
        for (int s = 0; s < 16; s++) acc[a][s] = 0.f;

    int jl = t >> 1;                   // 0..255  j row within chunk
    int dh = (t & 1) * 32;             // d half
    int rbase = w * 4;                 // local row base of this wave

    const float4* BT4 = (const float4*)BT;
    const float4* As4 = (const float4*)As;

    #pragma unroll
    for (int c = 0; c < 4; c++) {
        __syncthreads();               // previous chunk fully consumed (also covers As)
        // stage BT[d][j] = mixed[c*256+j][d]; lane pairs hit same bank at different
        // addr = 2-way conflict = free (m136)
        const float* src = mb + (size_t)(c * 256 + jl) * DD + dh;
        #pragma unroll
        for (int i = 0; i < 8; i++) {
            float4 v = *(const float4*)(src + i * 4);
            int d0 = dh + i * 4;
            BT[(d0 + 0) * 256 + jl] = v.x;
            BT[(d0 + 1) * 256 + jl] = v.y;
            BT[(d0 + 2) * 256 + jl] = v.z;
            BT[(d0 + 3) * 256 + jl] = v.w;
        }
        __syncthreads();
        // inner: per 4-d step, 4 contiguous b128 B-reads + 4 broadcast A-reads + 64 fma
        #pragma unroll 4
        for (int d4 = 0; d4 < 16; d4++) {
            float4 b0 = BT4[(d4 * 4 + 0) * 64 + lane];
            float4 b1 = BT4[(d4 * 4 + 1) * 64 + lane];
            float4 b2 = BT4[(d4 * 4 + 2) * 64 + lane];
            float4 b3 = BT4[(d4 * 4 + 3) * 64 + lane];
            #pragma unroll
            for (int rr = 0; rr < 4; rr++) {
                float4 a = As4[(rbase + rr) * 16 + d4];
                acc[rr][c * 4 + 0] = fmaf(a.w, b3.x, fmaf(a.z, b2.x, fmaf(a.y, b1.x, fmaf(a.x, b0.x, acc[rr][c * 4 + 0]))));
                acc[rr][c * 4 + 1] = fmaf(a.w, b3.y, fmaf(a.z, b2.y, fmaf(a.y, b1.y, fmaf(a.x, b0.y, acc[rr][c * 4 + 1]))));
                acc[rr][c * 4 + 2] = fmaf(a.w, b3.z, fmaf(a.z, b2.z, fmaf(a.y, b1.z, fmaf(a.x, b0.z, acc[rr][c * 4 + 2]))));
                acc[rr][c * 4 + 3] = fmaf(a.w, b3.w, fmaf(a.z, b2.w, fmaf(a.y, b1.w, fmaf(a.x, b0.w, acc[rr][c * 4 + 3]))));
            }
        }
    }
    __syncthreads();                   // BT dead -> reuse as selection scratch

    unsigned* skeyW = (unsigned*)&BT[w * 64];         // [8][64]
    int*      sjjW  = (int*)&BT[512 + w * 64];        // [8][64]

    float ssum = 0.f, qsum = 0.f;

    #pragma unroll 1
    for (int rr = 0; rr < 4; rr++) {
        int n = i0 + rbase + rr;       // node within batch
        int r = (b << 10) + n;         // global row

        // ordered-uint keys from registers (static acc indexing per branch)
        unsigned uk[16];
        #define EXTRACT_ROW(RRC) \
            _Pragma("unroll") \
            for (int s = 0; s < 16; s++) { \
                unsigned u = __float_as_uint(acc[RRC][s]); \
                uk[s] = u ^ (((unsigned)((int)u >> 31)) | 0x80000000u); \
            }
        if (rr == 0)      { EXTRACT_ROW(0) }
        else if (rr == 1) { EXTRACT_ROW(1) }
        else if (rr == 2) { EXTRACT_ROW(2) }
        else              { EXTRACT_ROW(3) }

        // per-lane max -> bitonic sort-64 desc -> tau = 20th largest lane-max
        unsigned mx = uk[0];
        #pragma unroll
        for (int i = 1; i < 16; i++) mx = uk[i] > mx ? uk[i] : mx;
        unsigned sv = mx;
        #pragma unroll
        for (int blk = 2; blk <= 64; blk <<= 1) {
            #pragma unroll
            for (int dist = blk >> 1; dist >= 1; dist >>= 1) {
                unsigned pv = (unsigned)__shfl_xor((int)sv, dist);
                bool up = (lane & blk) == 0;
                bool upper = (lane & dist) == 0;
                bool gt = sv > pv;
                sv = ((gt == upper) == up) ? sv : pv;
            }
        }
        unsigned tau = (unsigned)__shfl((int)sv, 19);

        // ballot-prefix compact candidates >= tau
        int base = 0;
        #pragma unroll
        for (int s = 0; s < 16; s++) {
            bool q = uk[s] >= tau;
            unsigned long long m = __ballot(q);
            if (q) {
                int pos = base + __popcll(m & ((1ull << lane) - 1ull));
                if (pos < 64) {
                    skeyW[pos] = uk[s];
                    sjjW[pos] = ((s >> 2) << 8) + lane * 4 + (s & 3);
                }
            }
            base += __popcll(m);
        }
        int C = base;   // >= 20 guaranteed

        float vk = -INFINITY; int ik = 0;
        if (C <= 64) {
            unsigned ck = 0u; int cj = 0x7FFFFFFF;
            if (lane < C) { ck = skeyW[lane]; cj = sjjW[lane]; }
            if (C <= 32) {
                #pragma unroll
                for (int blk = 2; blk <= 32; blk <<= 1)
                    #pragma unroll
                    for (int dist = blk >> 1; dist >= 1; dist >>= 1) {
                        unsigned pk = (unsigned)__shfl_xor((int)ck, dist);
                        int pj = __shfl_xor(cj, dist);
                        bool up = (lane & blk) == 0;
                        bool upper = (lane & dist) == 0;
                        bool gt = (ck > pk) || (ck == pk && cj < pj);
                        bool keep = ((gt == upper) == up);
                        ck = keep ? ck : pk; cj = keep ? cj : pj;
                    }
            } else {
                #pragma unroll
                for (int blk = 2; blk <= 64; blk <<= 1)
                    #pragma unroll
                    for (int dist = blk >> 1; dist >= 1; dist >>= 1) {
                        unsigned pk = (unsigned)__shfl_xor((int)ck, dist);
                        int pj = __shfl_xor(cj, dist);
                        bool up = (lane & blk) == 0;
                        bool upper = (lane & dist) == 0;
                        bool gt = (ck > pk) || (ck == pk && cj < pj);
                        bool keep = ((gt == upper) == up);
                        ck = keep ? ck : pk; cj = keep ? cj : pj;
                    }
            }
            if (lane < KK) {
                unsigned u = (ck & 0x80000000u) ? (ck ^ 0x80000000u) : ~ck;
                vk = __uint_as_float(u);
                ik = cj;
            }
        } else {
            // rare fallback: full 20-round extraction
            for (int k = 0; k < KK; k++) {
                unsigned bm = uk[0]; int bsl = 0;
                #pragma unroll
                for (int i = 1; i < 16; i++) if (uk[i] > bm) { bm = uk[i]; bsl = i; }
                unsigned wm = bm;
                #pragma unroll
                for (int off = 32; off; off >>= 1) {
                    unsigned tt = (unsigned)__shfl_xor((int)wm, off);
                    wm = tt > wm ? tt : wm;
                }
                unsigned long long ball = __ballot(bm == wm);
                int winner = (int)__builtin_ctzll(ball);
                int slotw = __shfl(bsl, winner);
                int jw = ((slotw >> 2) << 8) + winner * 4 + (slotw & 3);
                unsigned u2 = (wm & 0x80000000u) ? (wm ^ 0x80000000u) : ~wm;
                if (lane == k) { vk = __uint_as_float(u2); ik = jw; }
                if (lane == winner) uk[bsl] = 0u;
            }
        }

        // ---- GAT (operands in registers) ----
        float m1 = wave_max(vk);
        float ek = (lane < KK) ? expf(vk - m1) : 0.f;
        float s1v = wave_sum(ek);
        float wk = ek / s1v;
        float si = s_i[r], sjn = s_j[r];
        float a = -INFINITY;
        if (lane < KK) {
            float sjk = s_j[(b << 10) + ik];
            float t2 = si + sjk;
            a = (ik == n) ? -INFINITY : (t2 > 0.f ? t2 : 0.2f * t2);
        }
        float ts = si + sjn;
        float aself = ts > 0.f ? ts : 0.2f * ts;
        float am = wave_max(fmaxf(a, aself));
        float ea = (lane < KK && a != -INFINITY) ? expf(a - am) : 0.f;
        float es = expf(aself - am);
        float sm = wave_sum(ea) + es;
        float wnb = (ea / sm) * wk;
        float wself = es / sm;
        float gacc = b_gnn[lane] + wself * x_lin[(size_t)r * DD + lane];
        #pragma unroll
        for (int k = 0; k < KK; k++) {
            int jk = __shfl(ik, k);
            float wv = __shfl(wnb, k);
            gacc = fmaf(wv, x_lin[((size_t)(b << 10) + jk) * DD + lane], gacc);
        }
        gnn_pre[(size_t)r * DD + lane] = gacc;
        ssum += gacc;
        qsum = fmaf(gacc, gacc, qsum);
    }

    // bn1 per-channel partial stats (lane == channel), block-reduce then atomics
    float* ps = &BT[1024];   // [8][64]
    float* pq = &BT[1536];   // [8][64]
    ps[w * 64 + lane] = ssum;
    pq[w * 64 + lane] = qsum;
    __syncthreads();
    if (w == 0) {
        float s = 0.f, q2 = 0.f;
        #pragma unroll
        for (int k2 = 0; k2 < 8; k2++) { s += ps[k2 * 64 + lane]; q2 += pq[k2 * 64 + lane]; }
        atomicAdd(&stats[lane], s);
        atomicAdd(&stats[DD + lane], q2);
    }
}

// ---------------- K7: bn1 + relu + embed multiply (+ bno stats partials) ----------------
__global__ __launch_bounds__(256) void k_bn1(
    const float* __restrict__ gnn_pre, float* __restrict__ stats,
    const float* __restrict__ gamma, const float* __restrict__ beta,
    const float* __restrict__ net, float* __restrict__ out_pre)
{
    int tid = threadIdx.x;
    int d0 = (tid & 15) * 4;
    float mean4[4], rs4[4], bt4[4];
    #pragma unroll
    for (int k = 0; k < 4; k++) {
        float mu = stats[d0 + k] * (1.0f / BNROWS);
        float var = stats[64 + d0 + k] * (1.0f / BNROWS) - mu * mu;
        mean4[k] = mu;
        rs4[k] = rsqrtf(var + 1e-5f) * gamma[d0 + k];
        bt4[k] = beta[d0 + k];
    }
    float s4[4] = {0, 0, 0, 0}, q4[4] = {0, 0, 0, 0};
    size_t base4 = (size_t)blockIdx.x * 2048;     // float4 units (128 rows/block)
    #pragma unroll
    for (int i = 0; i < 8; i++) {
        size_t f4 = base4 + (size_t)i * 256 + tid;
        float4 v = ((const float4*)gnn_pre)[f4];
        int n = ((int)(f4 >> 4)) & 1023;
        float4 nv = ((const float4*)net)[(size_t)n * 16 + (tid & 15)];
        float vv[4] = {v.x, v.y, v.z, v.w};
        float nn2[4] = {nv.x, nv.y, nv.z, nv.w};
        float ov[4];
        #pragma unroll
        for (int k = 0; k < 4; k++) {
            float y = (vv[k] - mean4[k]) * rs4[k] + bt4[k];
            y = y > 0.f ? y : 0.f;
            float o = y * nn2[k];
            ov[k] = o;
            s4[k] += o;
            q4[k] = fmaf(o, o, q4[k]);
        }
        float4 o4 = {ov[0], ov[1], ov[2], ov[3]};
        ((float4*)out_pre)[f4] = o4;
    }
    __shared__ float4 ls[256], lq[256];
    ls[tid] = make_float4(s4[0], s4[1], s4[2], s4[3]);
    lq[tid] = make_float4(q4[0], q4[1], q4[2], q4[3]);
    __syncthreads();
    if (tid < 16) {
        float4 S = ls[tid], Q = lq[tid];
        #pragma unroll
        for (int rr = 1; rr < 16; rr++) {
            float4 a = ls[tid + 16 * rr], b = lq[tid + 16 * rr];
            S.x += a.x; S.y += a.y; S.z += a.z; S.w += a.w;
            Q.x += b.x; Q.y += b.y; Q.z += b.z; Q.w += b.w;
        }
        atomicAdd(&stats[128 + tid * 4 + 0], S.x);
        atomicAdd(&stats[128 + tid * 4 + 1], S.y);
        atomicAdd(&stats[128 + tid * 4 + 2], S.z);
        atomicAdd(&stats[128 + tid * 4 + 3], S.w);
        atomicAdd(&stats[192 + tid * 4 + 0], Q.x);
        atomicAdd(&stats[192 + tid * 4 + 1], Q.y);
        atomicAdd(&stats[192 + tid * 4 + 2], Q.z);
        atomicAdd(&stats[192 + tid * 4 + 3], Q.w);
    }
}

// ---------------- K8: bn_out + relu + head ----------------
__global__ __launch_bounds__(256) void k_head(
    const float* __restrict__ out_pre, const float* __restrict__ stats,
    const float* __restrict__ gamma, const float* __restrict__ beta,
    const float* __restrict__ W_out, const float* __restrict__ b_out,
    float* __restrict__ out)
{
    int w = threadIdx.x >> 6, lane = threadIdx.x & 63;
    int r = blockIdx.x * 4 + w;
    float mean = stats[lane] * (1.0f / BNROWS);
    float var = stats[DD + lane] * (1.0f / BNROWS) - mean * mean;
    float rs = rsqrtf(var + 1e-5f);
    float y = (out_pre[(size_t)r * DD + lane] - mean) * rs * gamma[lane] + beta[lane];
    y = y > 0.f ? y : 0.f;
    float p = wave_sum(y * W_out[lane]);
    if (lane == 0) out[r] = p + b_out[0];
}

extern "C" void kernel_launch(void* const* d_in, const int* in_sizes, int n_in,
                              void* d_out, int out_size, void* d_ws, size_t ws_size,
                              hipStream_t stream)
{
    const float* data     = (const float*)d_in[0];
    const float* gumbel   = (const float*)d_in[1];
    const float* W_cond   = (const float*)d_in[2];
    const float* b_cond   = (const float*)d_in[3];
    const float* W_ap     = (const float*)d_in[4];
    const float* b_ap     = (const float*)d_in[5];
    const float* W_av     = (const float*)d_in[6];
    const float* W_r      = (const float*)d_in[7];
    const float* b_r      = (const float*)d_in[8];
    const float* e_base   = (const float*)d_in[9];
    const float* lr_u     = (const float*)d_in[10];
    const float* lr_v     = (const float*)d_in[11];
    const float* W_gnn    = (const float*)d_in[12];
    const float* att_i    = (const float*)d_in[13];
    const float* att_j    = (const float*)d_in[14];
    const float* att_em_i = (const float*)d_in[15];
    const float* att_em_j = (const float*)d_in[16];
    const float* b_gnn    = (const float*)d_in[17];
    const float* bn1_g    = (const float*)d_in[18];
    const float* bn1_b    = (const float*)d_in[19];
    const float* net      = (const float*)d_in[20];
    const float* bno_g    = (const float*)d_in[21];
    const float* bno_b    = (const float*)d_in[22];
    const float* W_out    = (const float*)d_in[23];
    const float* b_out    = (const float*)d_in[24];

    float* ws = (float*)d_ws;
    float* h_it   = ws + OFF_HIT;
    float* x_lin  = ws + OFF_XLIN;
    float* e_it   = ws + OFF_EIT;
    float* pi_t   = ws + OFF_PIT;
    float* mixed  = ws + OFF_MIXED;
    float* s_i    = ws + OFF_SI;
    float* s_j    = ws + OFF_SJ;
    float* gnn_pre = ws + OFF_GNN;
    float* out_pre = ws + OFF_OUTP;
    float* stats   = ws + OFF_STAT;          // 256 stats
    float* pnum    = stats + 256;            // 2048
    float* pden    = stats + 2304;           // 32

    float* out0    = (float*)d_out;
    float* h_sys   = out0 + BB * NN;              // 32768
    float* pi_soft = out0 + BB * NN + BB * DD;    // 34816

    k_rows<<<BNROWS / 4, 256, 0, stream>>>(data, W_cond, b_cond, W_ap, b_ap, W_av, W_gnn,
                                           h_it, x_lin, e_it, stats);
    k_pool2<<<BB * 8, 256, 0, stream>>>(e_it, h_it, pnum, pden);
    k_route<<<1, 256, 0, stream>>>(pnum, pden, W_r, b_r, gumbel, h_sys, pi_soft, pi_t);
    k_mixed<<<BNROWS / 4, 256, 0, stream>>>(e_base, lr_u, lr_v, pi_t, x_lin,
                                            att_i, att_j, att_em_i, att_em_j, mixed, s_i, s_j);
    // fused score-GEMM + top-20 + GAT + bn1-stats: 32 rows/block, 1024 blocks
    k_fused<<<BB * 32, 512, 0, stream>>>(mixed, x_lin, s_i, s_j, b_gnn, gnn_pre, stats);
    k_bn1<<<256, 256, 0, stream>>>(gnn_pre, stats, bn1_g, bn1_b, net, out_pre);
    k_head<<<BNROWS / 4, 256, 0, stream>>>(out_pre, stats + 128, bno_g, bno_b, W_out, b_out, out0);
}